// Round 4
// baseline (232.645 us; speedup 1.0000x reference)
//
#include <hip/hip_runtime.h>
#include <hip/hip_bf16.h>

#define NB   4
#define MD   2048
#define KD   2048
#define ND   2048

// fallback (fused) kernel tile
#define BM   128
#define BN   128

typedef short bf16x8 __attribute__((ext_vector_type(8)));
typedef float f32x4  __attribute__((ext_vector_type(4)));
typedef unsigned int u32;

#define MFMA16(a, b, c) __builtin_amdgcn_mfma_f32_16x16x32_bf16(a, b, c, 0, 0, 0)
#define BAR()    __builtin_amdgcn_s_barrier()
#define PRIO(n)  __builtin_amdgcn_s_setprio(n)
#define WAITV(n) asm volatile("s_waitcnt vmcnt(" #n ")" ::: "memory")

// pack two fp32 -> one dword of 2 bf16 (RNE)
__device__ __forceinline__ unsigned pk2(float lo, float hi) {
    union { __hip_bfloat162 h2; unsigned u; } c;
    c.h2 = __float22bfloat162_rn(make_float2(lo, hi));
    return c.u;
}

__device__ __forceinline__ void gload_lds16(const void* g, void* l) {
    __builtin_amdgcn_global_load_lds(
        (const __attribute__((address_space(1))) u32*)g,
        (__attribute__((address_space(3))) u32*)l,
        16, 0, 0);
}

// ---- Phase 1 (fused): A fp32->bf16 cast (8 elem/thread)  +  B -> BT bf16 ----
#define NCAST ((NB * MD * KD / 8) / 256)   // 8192 cast blocks (uint4 out/thread)

__global__ __launch_bounds__(256) void prep_kernel(
    const float* __restrict__ A, const float* __restrict__ B,
    unsigned short* __restrict__ Abf, unsigned short* __restrict__ BT)
{
    __shared__ float t[64][65];   // transpose tile; +1 pad -> <=2-way conflicts (free)
    const int tid = threadIdx.x;

    if (blockIdx.x < NCAST) {
        const size_t idx = (size_t)blockIdx.x * 256 + tid;   // uint4 (8 bf16) index
        const float4 v0 = ((const float4*)A)[2 * idx];
        const float4 v1 = ((const float4*)A)[2 * idx + 1];
        uint4 w;
        w.x = pk2(v0.x, v0.y); w.y = pk2(v0.z, v0.w);
        w.z = pk2(v1.x, v1.y); w.w = pk2(v1.z, v1.w);
        ((uint4*)Abf)[idx] = w;
        return;
    }
    const int bx  = blockIdx.x - NCAST;      // 0..4095
    const int b   = bx >> 10;                // batch (1024 tiles per batch)
    const int rem = bx & 1023;
    const int k0  = (rem & 31) * 64;
    const int n0  = (rem >> 5) * 64;

    const float* Bb = B + (size_t)b * KD * ND;
    const int rk = tid >> 4;                 // 0..15, +16/pass
    const int rn = (tid & 15) * 4;
    #pragma unroll
    for (int p = 0; p < 4; ++p) {
        const int kl = p * 16 + rk;
        const float4 v = *(const float4*)(Bb + (size_t)(k0 + kl) * ND + n0 + rn);
        t[kl][rn + 0] = v.x; t[kl][rn + 1] = v.y;
        t[kl][rn + 2] = v.z; t[kl][rn + 3] = v.w;
    }
    __syncthreads();
    const int wn = tid >> 2;                 // 0..63 (owns column n)
    const int wk = (tid & 3) * 16;           // 16 consecutive k
    float f[16];
    #pragma unroll
    for (int j = 0; j < 16; ++j) f[j] = t[wk + j][wn];
    uint4 w0, w1;
    w0.x = pk2(f[0], f[1]);   w0.y = pk2(f[2], f[3]);
    w0.z = pk2(f[4], f[5]);   w0.w = pk2(f[6], f[7]);
    w1.x = pk2(f[8], f[9]);   w1.y = pk2(f[10], f[11]);
    w1.z = pk2(f[12], f[13]); w1.w = pk2(f[14], f[15]);
    unsigned short* dst = BT + (size_t)b * ND * KD + (size_t)(n0 + wn) * KD + k0 + wk;
    *(uint4*)(dst) = w0;
    *(uint4*)(dst + 8) = w1;
}

// ---------------------------------------------------------------------------
// Phase 2 (round 4): 256x256 tile, BK=64, 8 waves (2M x 4N).
//
// R3 post-mortem: fat phases got 43.5% MfmaUtil; remaining gap is the
// per-phase WAITL(0) full drain serializing {LDS reads} + {MFMA} per wave
// (per-tile: 2484 cyc MFMA + ~2x1150 cyc exposed LDS wait = 4725 measured).
// R4: drop manual lgkm drains entirely; issue frag reads in consumer order
// inside a bounded register window and let the compiler's fine-grained
// per-use lgkmcnt overlap reads under the previous 16-MFMA block.
// Window keeps peak live frags ~16 (R3 sits at 116 VGPR + 128 acc AGPR =
// 244/256; a full 24-frag prefetch would spill).
// Per tile: 1 vmcnt(0)+barrier (entry), stages A(t+1) after entry, B(t+1)
// mid-tile -> drained loads have >=1 tile (~3000 cyc) of slack.
// Keeps: T2 XOR swizzle (0 conflicts), XCD-bijective swizzle (FETCH 49 MB),
// setprio around MFMA blocks.
// ---------------------------------------------------------------------------

// Stage one full 256x64 tile: 4 rounds of (64 rows x 128 B), 512 thr x 16 B.
// LDS dest linear in tid; global source column pre-swizzled (rule #21).
#define STAGE4(dstbase, bufoff, gbase, tile) do {                            \
    _Pragma("unroll")                                                        \
    for (int rr_ = 0; rr_ < 4; ++rr_) {                                      \
        gload_lds16((gbase) + (size_t)(rr_ * 64 + s_row) * KD                \
                            + (size_t)(tile) * 64 + s_col,                   \
                    (dstbase) + (bufoff) + rr_ * 4096 + tid * 8);            \
    }                                                                        \
} while (0)

// One K=64 tile: windowed frag reads + 4x16 MFMA blocks.
#define TILE_BODY(aP, bP, STGA, STGB) do {                                   \
    bf16x8 B0_[4], B1_[4], A0_[8], A1_[8];                                   \
    STGA;                                                                    \
    _Pragma("unroll")                                                        \
    for (int n_ = 0; n_ < 4; ++n_)                                           \
        B0_[n_] = *(const bf16x8*)((bP) + n_ * (16 * 64) + koff0);           \
    _Pragma("unroll")                                                        \
    for (int m_ = 0; m_ < 8; ++m_)                                           \
        A0_[m_] = *(const bf16x8*)((aP) + m_ * (16 * 64) + koff0);           \
    /* block 1: m 0..3 x ks0 (covers A0 hi + B1/A1-lo read latency) */       \
    PRIO(1);                                                                 \
    _Pragma("unroll")                                                        \
    for (int m_ = 0; m_ < 4; ++m_)                                           \
        _Pragma("unroll")                                                    \
        for (int n_ = 0; n_ < 4; ++n_)                                       \
            acc[m_][n_] = MFMA16(A0_[m_], B0_[n_], acc[m_][n_]);             \
    PRIO(0);                                                                 \
    _Pragma("unroll")                                                        \
    for (int n_ = 0; n_ < 4; ++n_)                                           \
        B1_[n_] = *(const bf16x8*)((bP) + n_ * (16 * 64) + koff1);           \
    _Pragma("unroll")                                                        \
    for (int m_ = 0; m_ < 4; ++m_)                                           \
        A1_[m_] = *(const bf16x8*)((aP) + m_ * (16 * 64) + koff1);           \
    /* block 2: m 4..7 x ks0 */                                              \
    PRIO(1);                                                                 \
    _Pragma("unroll")                                                        \
    for (int m_ = 4; m_ < 8; ++m_)                                           \
        _Pragma("unroll")                                                    \
        for (int n_ = 0; n_ < 4; ++n_)                                       \
            acc[m_][n_] = MFMA16(A0_[m_], B0_[n_], acc[m_][n_]);             \
    PRIO(0);                                                                 \
    STGB;                                                                    \
    _Pragma("unroll")                                                        \
    for (int m_ = 4; m_ < 8; ++m_)                                           \
        A1_[m_] = *(const bf16x8*)((aP) + m_ * (16 * 64) + koff1);           \
    /* block 3: m 0..3 x ks1 */                                              \
    PRIO(1);                                                                 \
    _Pragma("unroll")                                                        \
    for (int m_ = 0; m_ < 4; ++m_)                                           \
        _Pragma("unroll")                                                    \
        for (int n_ = 0; n_ < 4; ++n_)                                       \
            acc[m_][n_] = MFMA16(A1_[m_], B1_[n_], acc[m_][n_]);             \
    /* block 4: m 4..7 x ks1 */                                              \
    _Pragma("unroll")                                                        \
    for (int m_ = 4; m_ < 8; ++m_)                                           \
        _Pragma("unroll")                                                    \
        for (int n_ = 0; n_ < 4; ++n_)                                       \
            acc[m_][n_] = MFMA16(A1_[m_], B1_[n_], acc[m_][n_]);             \
    PRIO(0);                                                                 \
} while (0)

#define NOPST ((void)0)

__global__ __launch_bounds__(512, 2) void gemm256_kernel(
    const unsigned short* __restrict__ Abf, const unsigned short* __restrict__ BT,
    float* __restrict__ C)
{
    __shared__ __align__(16) unsigned short As[2][256][64];   // 64 KB
    __shared__ __align__(16) unsigned short Bs[2][256][64];   // 64 KB

    const int tid = threadIdx.x;

    // XCD-bijective chunked swizzle: 256 wgs, 8 XCDs, 32 wgs/XCD.
    const int wg    = blockIdx.x;
    const int lin   = ((wg & 7) << 5) | (wg >> 3);
    const int batch = lin >> 6;
    const int rem   = lin & 63;
    const int row0  = (rem >> 3) * 256;
    const int col0  = (rem & 7) * 256;

    const unsigned short* __restrict__ Abase =
        Abf + (size_t)batch * MD * KD + (size_t)row0 * KD;
    const unsigned short* __restrict__ Bbase =
        BT  + (size_t)batch * ND * KD + (size_t)col0 * KD;
    float* __restrict__ Cbase =
        C + (size_t)batch * MD * ND + (size_t)row0 * ND + col0;

    const int wave = tid >> 6;
    const int lane = tid & 63;
    const int q    = lane >> 4;          // 0..3
    const int r    = lane & 15;          // 0..15
    const int wm   = (wave >> 2) * 128;  // 0 / 128
    const int wn   = (wave & 3)  * 64;   // 0,64,128,192

    // staging geometry: per round 512 thr x 16 B = 64 rows x 128 B
    const int s_row = tid >> 3;                            // 0..63
    const int s_col = ((tid & 7) ^ (s_row & 7)) * 8;       // pre-swizzled src col (elems)

    // swizzled frag-read offsets (elems): logical slot ks*4+q -> ^ (r&7)
    const int rb    = r & 7;
    const int koff0 = ((q    ) ^ rb) * 8;                  // k-slice 0
    const int koff1 = ((4 + q) ^ rb) * 8;                  // k-slice 1

    unsigned short* As0 = &As[0][0][0];
    unsigned short* Bs0 = &Bs[0][0][0];
    const unsigned short* aR0 = &As[0][wm + r][0];
    const unsigned short* aR1 = &As[1][wm + r][0];
    const unsigned short* bR0 = &Bs[0][wn + r][0];
    const unsigned short* bR1 = &Bs[1][wn + r][0];

    f32x4 acc[8][4];
    #pragma unroll
    for (int m = 0; m < 8; ++m)
        #pragma unroll
        for (int n = 0; n < 4; ++n)
            acc[m][n] = (f32x4){0.f, 0.f, 0.f, 0.f};

    // prologue: stage tile 0 into buf 0
    STAGE4(As0, 0, Abase, 0);
    STAGE4(Bs0, 0, Bbase, 0);

    for (int t = 0; t < 31; ++t) {
        WAITV(0); BAR();                       // tile t resident in buf t&1
        const int nxtoff = ((t & 1) ^ 1) * (256 * 64);
        const unsigned short* aP = (t & 1) ? aR1 : aR0;
        const unsigned short* bP = (t & 1) ? bR1 : bR0;
        TILE_BODY(aP, bP,
                  STAGE4(As0, nxtoff, Abase, t + 1),
                  STAGE4(Bs0, nxtoff, Bbase, t + 1));
    }
    // peeled tile 31 (buf 1), no further stages
    WAITV(0); BAR();
    TILE_BODY(aR1, bR1, NOPST, NOPST);

    // epilogue: C/D layout col=lane&15, row=quad*4+reg (m89-verified)
    #pragma unroll
    for (int m = 0; m < 8; ++m)
        #pragma unroll
        for (int n = 0; n < 4; ++n)
            #pragma unroll
            for (int j = 0; j < 4; ++j) {
                const int row = wm + m * 16 + q * 4 + j;
                const int col = wn + n * 16 + r;
                Cbase[(size_t)row * ND + col] = acc[m][n][j];
            }
}

// ---- Fallback (ws too small): fused fp32-staging kernel ----
#define LSTR 40
__global__ __launch_bounds__(256, 4) void fused_kernel(
    const float* __restrict__ A, const float* __restrict__ Bmat,
    float* __restrict__ C)
{
    __shared__ unsigned short Asf[BM][LSTR];
    __shared__ unsigned short Bsf[BN][LSTR];
    const int tid   = threadIdx.x;
    const int batch = blockIdx.z;
    const int row0  = blockIdx.y * BM;
    const int col0  = blockIdx.x * BN;
    const float* Abase = A    + (size_t)batch * MD * KD + (size_t)row0 * KD;
    const float* Bbase = Bmat + (size_t)batch * KD * ND + col0;
    float*       Cbase = C    + (size_t)batch * MD * ND + (size_t)row0 * ND + col0;
    const int a_row = tid >> 3, a_kc = (tid & 7) * 4;
    const int b_n = tid & 127, b_kh = (tid >> 7) * 16;
    const float* Bcol = Bbase + b_n;
    const int wave = tid >> 6, lane = tid & 63, q = lane >> 4, r = lane & 15;
    const int wm = (wave >> 1) * 64, wn = (wave & 1) * 64;
    f32x4 acc[4][4];
    #pragma unroll
    for (int i = 0; i < 4; ++i)
        #pragma unroll
        for (int j = 0; j < 4; ++j) acc[i][j] = (f32x4){0.f, 0.f, 0.f, 0.f};
    for (int k0 = 0; k0 < KD; k0 += 32) {
        #pragma unroll
        for (int i = 0; i < 4; ++i) {
            const int row = a_row + i * 32;
            const float4 v = *(const float4*)(Abase + (size_t)row * KD + k0 + a_kc);
            uint2 w; w.x = pk2(v.x, v.y); w.y = pk2(v.z, v.w);
            *(uint2*)&Asf[row][a_kc] = w;
        }
        #pragma unroll
        for (int h = 0; h < 2; ++h) {
            const int kb = b_kh + h * 8;
            float bv[8];
            #pragma unroll
            for (int j = 0; j < 8; ++j) bv[j] = Bcol[(size_t)(k0 + kb + j) * ND];
            uint4 w;
            w.x = pk2(bv[0], bv[1]); w.y = pk2(bv[2], bv[3]);
            w.z = pk2(bv[4], bv[5]); w.w = pk2(bv[6], bv[7]);
            *(uint4*)&Bsf[b_n][kb] = w;
        }
        __syncthreads();
        bf16x8 a_frag[4], b_frag[4];
        #pragma unroll
        for (int im = 0; im < 4; ++im)
            a_frag[im] = *(const bf16x8*)&Asf[wm + im * 16 + r][q * 8];
        #pragma unroll
        for (int in = 0; in < 4; ++in)
            b_frag[in] = *(const bf16x8*)&Bsf[wn + in * 16 + r][q * 8];
        #pragma unroll
        for (int im = 0; im < 4; ++im)
            #pragma unroll
            for (int in = 0; in < 4; ++in)
                acc[im][in] = MFMA16(a_frag[im], b_frag[in], acc[im][in]);
        __syncthreads();
    }
    #pragma unroll
    for (int im = 0; im < 4; ++im)
        #pragma unroll
        for (int in = 0; in < 4; ++in)
            #pragma unroll
            for (int j = 0; j < 4; ++j)
                Cbase[(size_t)(wm + im * 16 + q * 4 + j) * ND + wn + in * 16 + r]
                    = acc[im][in][j];
}

extern "C" void kernel_launch(void* const* d_in, const int* in_sizes, int n_in,
                              void* d_out, int out_size, void* d_ws, size_t ws_size,
                              hipStream_t stream) {
    const float* a = (const float*)d_in[0];
    const float* b = (const float*)d_in[1];
    float* out = (float*)d_out;

    const size_t abf_bytes = (size_t)NB * MD * KD * 2;   // 32 MB
    const size_t bt_bytes  = (size_t)NB * KD * ND * 2;   // 32 MB

    if (ws_size >= abf_bytes + bt_bytes) {
        unsigned short* Abf = (unsigned short*)d_ws;
        unsigned short* BT  = (unsigned short*)((char*)d_ws + abf_bytes);
        prep_kernel<<<dim3(NCAST + NB * (KD / 64) * (ND / 64)), dim3(256), 0, stream>>>(
            a, b, Abf, BT);
        const int nwg = (MD / 256) * (ND / 256) * NB;    // 256
        gemm256_kernel<<<dim3(nwg), dim3(512), 0, stream>>>(Abf, BT, out);
    } else {
        fused_kernel<<<dim3(ND / BN, BM ? MD / BM : 1, NB), dim3(256), 0, stream>>>(a, b, out);
    }
}

// Round 5
// 220.525 us; speedup vs baseline: 1.0550x; 1.0550x over previous
//
#include <hip/hip_runtime.h>
#include <hip/hip_bf16.h>

#define NB   4
#define MD   2048
#define KD   2048
#define ND   2048

// fallback (fused) kernel tile
#define BM   128
#define BN   128

typedef short bf16x8 __attribute__((ext_vector_type(8)));
typedef float f32x4  __attribute__((ext_vector_type(4)));
typedef unsigned int u32;

#define MFMA16(a, b, c) __builtin_amdgcn_mfma_f32_16x16x32_bf16(a, b, c, 0, 0, 0)
#define BAR()    __builtin_amdgcn_s_barrier()
#define PRIO(n)  __builtin_amdgcn_s_setprio(n)
#define WAITV(n) asm volatile("s_waitcnt vmcnt(" #n ")" ::: "memory")
#define SCHEDB() __builtin_amdgcn_sched_barrier(0)
#define ESYNC    do { WAITV(0); BAR(); } while (0)
#define ENON     ((void)0)

// pack two fp32 -> one dword of 2 bf16 (RNE)
__device__ __forceinline__ unsigned pk2(float lo, float hi) {
    union { __hip_bfloat162 h2; unsigned u; } c;
    c.h2 = __float22bfloat162_rn(make_float2(lo, hi));
    return c.u;
}

__device__ __forceinline__ void gload_lds16(const void* g, void* l) {
    __builtin_amdgcn_global_load_lds(
        (const __attribute__((address_space(1))) u32*)g,
        (__attribute__((address_space(3))) u32*)l,
        16, 0, 0);
}

// ---- Phase 1 (fused): A fp32->bf16 cast (8 elem/thread)  +  B -> BT bf16 ----
#define NCAST ((NB * MD * KD / 8) / 256)   // 8192 cast blocks (uint4 out/thread)

__global__ __launch_bounds__(256) void prep_kernel(
    const float* __restrict__ A, const float* __restrict__ B,
    unsigned short* __restrict__ Abf, unsigned short* __restrict__ BT)
{
    __shared__ float t[64][65];   // transpose tile; +1 pad -> <=2-way conflicts (free)
    const int tid = threadIdx.x;

    if (blockIdx.x < NCAST) {
        const size_t idx = (size_t)blockIdx.x * 256 + tid;   // uint4 (8 bf16) index
        const float4 v0 = ((const float4*)A)[2 * idx];
        const float4 v1 = ((const float4*)A)[2 * idx + 1];
        uint4 w;
        w.x = pk2(v0.x, v0.y); w.y = pk2(v0.z, v0.w);
        w.z = pk2(v1.x, v1.y); w.w = pk2(v1.z, v1.w);
        ((uint4*)Abf)[idx] = w;
        return;
    }
    const int bx  = blockIdx.x - NCAST;      // 0..4095
    const int b   = bx >> 10;                // batch (1024 tiles per batch)
    const int rem = bx & 1023;
    const int k0  = (rem & 31) * 64;
    const int n0  = (rem >> 5) * 64;

    const float* Bb = B + (size_t)b * KD * ND;
    const int rk = tid >> 4;                 // 0..15, +16/pass
    const int rn = (tid & 15) * 4;
    #pragma unroll
    for (int p = 0; p < 4; ++p) {
        const int kl = p * 16 + rk;
        const float4 v = *(const float4*)(Bb + (size_t)(k0 + kl) * ND + n0 + rn);
        t[kl][rn + 0] = v.x; t[kl][rn + 1] = v.y;
        t[kl][rn + 2] = v.z; t[kl][rn + 3] = v.w;
    }
    __syncthreads();
    const int wn = tid >> 2;                 // 0..63 (owns column n)
    const int wk = (tid & 3) * 16;           // 16 consecutive k
    float f[16];
    #pragma unroll
    for (int j = 0; j < 16; ++j) f[j] = t[wk + j][wn];
    uint4 w0, w1;
    w0.x = pk2(f[0], f[1]);   w0.y = pk2(f[2], f[3]);
    w0.z = pk2(f[4], f[5]);   w0.w = pk2(f[6], f[7]);
    w1.x = pk2(f[8], f[9]);   w1.y = pk2(f[10], f[11]);
    w1.z = pk2(f[12], f[13]); w1.w = pk2(f[14], f[15]);
    unsigned short* dst = BT + (size_t)b * ND * KD + (size_t)(n0 + wn) * KD + k0 + wk;
    *(uint4*)(dst) = w0;
    *(uint4*)(dst + 8) = w1;
}

// ---------------------------------------------------------------------------
// Phase 2 (round 5): 256x256 tile, BK=64, 8 waves (2M x 4N), fat phases.
//
// R4 post-mortem: issuing global_load_lds BEFORE the ds_reads made the
// compiler's alias-conservative hazard pass insert s_waitcnt vmcnt(0)
// in front of the ds_reads -> every tile waited on the NEXT tile's HBM
// staging (31% MfmaUtil, back to R2 level). RULE: all ds_reads of the
// current buffer must precede the stage-issue in program order.
// R5 = R3's proven structure (43.5% util) with ONE change: the manual
// WAITL(0) full drain between stage and MFMA is removed; the compiler's
// fine-grained per-use lgkmcnt lets the first MFMAs start after ~5 of 12
// reads, overlapping LDS-read latency (~1150 cyc/phase, co-critical) under
// the 1242-cyc MFMA cluster. sched_barrier(0) after the stage pins the
// prefetch issue point below the reads and above the MFMA cluster.
// Phases per 2 tiles (ESYNC = vmcnt(0)+barrier at buffer switch only):
//   P1 [ESYNC] read buf0.ks0 | stage A(2j+1)->As[1] | 32 MFMA
//   P2         read buf0.ks1 | stage B(2j+1)->Bs[1] | 32 MFMA
//   P3 [ESYNC] read buf1.ks0 | stage A(2j+2)->As[0] | 32 MFMA
//   P4         read buf1.ks1 | stage B(2j+2)->Bs[0] | 32 MFMA
// Race ledger (unchanged from R3): a wave reaches each ESYNC barrier only
// after its MFMAs consumed its reads (lgkm data-dep), so post-barrier
// stages never overwrite live data; vmcnt(0)-before-barrier makes all
// waves' staged data visible after the barrier.
// Keeps: T2 XOR swizzle (0 conflicts), XCD-bijective swizzle (FETCH 49 MB),
// setprio around MFMA clusters.
// ---------------------------------------------------------------------------

// Stage one full 256x64 tile: 4 rounds of (64 rows x 128 B), 512 thr x 16 B.
// LDS dest linear in tid; global source column pre-swizzled (rule #21).
#define STAGE4(dst, buf, base, tile) do {                                    \
    _Pragma("unroll")                                                        \
    for (int rr_ = 0; rr_ < 4; ++rr_) {                                      \
        gload_lds16((base) + (size_t)(rr_ * 64 + s_row) * KD                 \
                           + (size_t)(tile) * 64 + s_col,                    \
                    &dst[buf][0][0] + rr_ * 4096 + tid * 8);                 \
    }                                                                        \
} while (0)

// One fat phase: 12 ds_read_b128 (4 B + 8 A frags) FIRST, then stage,
// then 32 indep MFMA (auto per-use lgkmcnt waits -- no manual drain).
#define PHASE(bufi, ksi, ENTRY, STG) do {                                    \
    ENTRY;                                                                   \
    const unsigned short* aP_ = (bufi) ? aR1 : aR0;                          \
    const unsigned short* bP_ = (bufi) ? bR1 : bR0;                          \
    const int ko_ = (ksi) ? koff1 : koff0;                                   \
    bf16x8 bfr_[4], afr_[8];                                                 \
    _Pragma("unroll")                                                        \
    for (int n_ = 0; n_ < 4; ++n_)                                           \
        bfr_[n_] = *(const bf16x8*)(bP_ + n_ * (16 * 64) + ko_);             \
    _Pragma("unroll")                                                        \
    for (int m_ = 0; m_ < 8; ++m_)                                           \
        afr_[m_] = *(const bf16x8*)(aP_ + m_ * (16 * 64) + ko_);             \
    STG;                                                                     \
    SCHEDB();                                                                \
    PRIO(1);                                                                 \
    _Pragma("unroll")                                                        \
    for (int m_ = 0; m_ < 8; ++m_)                                           \
        _Pragma("unroll")                                                    \
        for (int n_ = 0; n_ < 4; ++n_)                                       \
            acc[m_][n_] = MFMA16(afr_[m_], bfr_[n_], acc[m_][n_]);           \
    PRIO(0);                                                                 \
} while (0)

__global__ __launch_bounds__(512, 2) void gemm256_kernel(
    const unsigned short* __restrict__ Abf, const unsigned short* __restrict__ BT,
    float* __restrict__ C)
{
    __shared__ __align__(16) unsigned short As[2][256][64];   // 64 KB
    __shared__ __align__(16) unsigned short Bs[2][256][64];   // 64 KB

    const int tid = threadIdx.x;

    // XCD-bijective chunked swizzle: 256 wgs, 8 XCDs, 32 wgs/XCD.
    const int wg    = blockIdx.x;
    const int lin   = ((wg & 7) << 5) | (wg >> 3);
    const int batch = lin >> 6;
    const int rem   = lin & 63;
    const int row0  = (rem >> 3) * 256;
    const int col0  = (rem & 7) * 256;

    const unsigned short* __restrict__ Abase =
        Abf + (size_t)batch * MD * KD + (size_t)row0 * KD;
    const unsigned short* __restrict__ Bbase =
        BT  + (size_t)batch * ND * KD + (size_t)col0 * KD;
    float* __restrict__ Cbase =
        C + (size_t)batch * MD * ND + (size_t)row0 * ND + col0;

    const int wave = tid >> 6;
    const int lane = tid & 63;
    const int q    = lane >> 4;          // 0..3
    const int r    = lane & 15;          // 0..15
    const int wm   = (wave >> 2) * 128;  // 0 / 128
    const int wn   = (wave & 3)  * 64;   // 0,64,128,192

    // staging geometry: per round 512 thr x 16 B = 64 rows x 128 B
    const int s_row = tid >> 3;                            // 0..63
    const int s_col = ((tid & 7) ^ (s_row & 7)) * 8;       // pre-swizzled src col (elems)

    // swizzled frag-read offsets (elems): logical slot ks*4+q -> ^ (r&7)
    const int rb    = r & 7;
    const int koff0 = ((q    ) ^ rb) * 8;                  // k-slice 0
    const int koff1 = ((4 + q) ^ rb) * 8;                  // k-slice 1

    const unsigned short* aR0 = &As[0][wm + r][0];
    const unsigned short* aR1 = &As[1][wm + r][0];
    const unsigned short* bR0 = &Bs[0][wn + r][0];
    const unsigned short* bR1 = &Bs[1][wn + r][0];

    f32x4 acc[8][4];
    #pragma unroll
    for (int m = 0; m < 8; ++m)
        #pragma unroll
        for (int n = 0; n < 4; ++n)
            acc[m][n] = (f32x4){0.f, 0.f, 0.f, 0.f};

    // prologue: tile 0 only; the rolling pattern stages tile 1 in P1/P2
    STAGE4(As, 0, Abase, 0);
    STAGE4(Bs, 0, Bbase, 0);

    for (int j = 0; j < 15; ++j) {       // tiles 2j, 2j+1 ; stages 2j+1, 2j+2
        PHASE(0, 0, ESYNC, STAGE4(As, 1, Abase, 2 * j + 1));
        PHASE(0, 1, ENON,  STAGE4(Bs, 1, Bbase, 2 * j + 1));
        PHASE(1, 0, ESYNC, STAGE4(As, 0, Abase, 2 * j + 2));
        PHASE(1, 1, ENON,  STAGE4(Bs, 0, Bbase, 2 * j + 2));
    }
    // peeled tail: tiles 30, 31 (no stage beyond tile 31)
    PHASE(0, 0, ESYNC, STAGE4(As, 1, Abase, 31));
    PHASE(0, 1, ENON,  STAGE4(Bs, 1, Bbase, 31));
    PHASE(1, 0, ESYNC, ENON);
    PHASE(1, 1, ENON,  ENON);

    // epilogue: C/D layout col=lane&15, row=quad*4+reg (m89-verified)
    #pragma unroll
    for (int m = 0; m < 8; ++m)
        #pragma unroll
        for (int n = 0; n < 4; ++n)
            #pragma unroll
            for (int j = 0; j < 4; ++j) {
                const int row = wm + m * 16 + q * 4 + j;
                const int col = wn + n * 16 + r;
                Cbase[(size_t)row * ND + col] = acc[m][n][j];
            }
}

// ---- Fallback (ws too small): fused fp32-staging kernel ----
#define LSTR 40
__global__ __launch_bounds__(256, 4) void fused_kernel(
    const float* __restrict__ A, const float* __restrict__ Bmat,
    float* __restrict__ C)
{
    __shared__ unsigned short Asf[BM][LSTR];
    __shared__ unsigned short Bsf[BN][LSTR];
    const int tid   = threadIdx.x;
    const int batch = blockIdx.z;
    const int row0  = blockIdx.y * BM;
    const int col0  = blockIdx.x * BN;
    const float* Abase = A    + (size_t)batch * MD * KD + (size_t)row0 * KD;
    const float* Bbase = Bmat + (size_t)batch * KD * ND + col0;
    float*       Cbase = C    + (size_t)batch * MD * ND + (size_t)row0 * ND + col0;
    const int a_row = tid >> 3, a_kc = (tid & 7) * 4;
    const int b_n = tid & 127, b_kh = (tid >> 7) * 16;
    const float* Bcol = Bbase + b_n;
    const int wave = tid >> 6, lane = tid & 63, q = lane >> 4, r = lane & 15;
    const int wm = (wave >> 1) * 64, wn = (wave & 1) * 64;
    f32x4 acc[4][4];
    #pragma unroll
    for (int i = 0; i < 4; ++i)
        #pragma unroll
        for (int j = 0; j < 4; ++j) acc[i][j] = (f32x4){0.f, 0.f, 0.f, 0.f};
    for (int k0 = 0; k0 < KD; k0 += 32) {
        #pragma unroll
        for (int i = 0; i < 4; ++i) {
            const int row = a_row + i * 32;
            const float4 v = *(const float4*)(Abase + (size_t)row * KD + k0 + a_kc);
            uint2 w; w.x = pk2(v.x, v.y); w.y = pk2(v.z, v.w);
            *(uint2*)&Asf[row][a_kc] = w;
        }
        #pragma unroll
        for (int h = 0; h < 2; ++h) {
            const int kb = b_kh + h * 8;
            float bv[8];
            #pragma unroll
            for (int j = 0; j < 8; ++j) bv[j] = Bcol[(size_t)(k0 + kb + j) * ND];
            uint4 w;
            w.x = pk2(bv[0], bv[1]); w.y = pk2(bv[2], bv[3]);
            w.z = pk2(bv[4], bv[5]); w.w = pk2(bv[6], bv[7]);
            *(uint4*)&Bsf[b_n][kb] = w;
        }
        __syncthreads();
        bf16x8 a_frag[4], b_frag[4];
        #pragma unroll
        for (int im = 0; im < 4; ++im)
            a_frag[im] = *(const bf16x8*)&Asf[wm + im * 16 + r][q * 8];
        #pragma unroll
        for (int in = 0; in < 4; ++in)
            b_frag[in] = *(const bf16x8*)&Bsf[wn + in * 16 + r][q * 8];
        #pragma unroll
        for (int im = 0; im < 4; ++im)
            #pragma unroll
            for (int in = 0; in < 4; ++in)
                acc[im][in] = MFMA16(a_frag[im], b_frag[in], acc[im][in]);
        __syncthreads();
    }
    #pragma unroll
    for (int im = 0; im < 4; ++im)
        #pragma unroll
        for (int in = 0; in < 4; ++in)
            #pragma unroll
            for (int j = 0; j < 4; ++j)
                Cbase[(size_t)(wm + im * 16 + q * 4 + j) * ND + wn + in * 16 + r]
                    = acc[im][in][j];
}

extern "C" void kernel_launch(void* const* d_in, const int* in_sizes, int n_in,
                              void* d_out, int out_size, void* d_ws, size_t ws_size,
                              hipStream_t stream) {
    const float* a = (const float*)d_in[0];
    const float* b = (const float*)d_in[1];
    float* out = (float*)d_out;

    const size_t abf_bytes = (size_t)NB * MD * KD * 2;   // 32 MB
    const size_t bt_bytes  = (size_t)NB * KD * ND * 2;   // 32 MB

    if (ws_size >= abf_bytes + bt_bytes) {
        unsigned short* Abf = (unsigned short*)d_ws;
        unsigned short* BT  = (unsigned short*)((char*)d_ws + abf_bytes);
        prep_kernel<<<dim3(NCAST + NB * (KD / 64) * (ND / 64)), dim3(256), 0, stream>>>(
            a, b, Abf, BT);
        const int nwg = (MD / 256) * (ND / 256) * NB;    // 256
        gemm256_kernel<<<dim3(nwg), dim3(512), 0, stream>>>(Abf, BT, out);
    } else {
        fused_kernel<<<dim3(ND / BN, MD / BM, NB), dim3(256), 0, stream>>>(a, b, out);
    }
}